// Round 9
// baseline (516.616 us; speedup 1.0000x reference)
//
#include <hip/hip_runtime.h>

typedef unsigned long long u64;
typedef unsigned int u32;
typedef float  floatx4 __attribute__((ext_vector_type(4)));
typedef short  short8  __attribute__((ext_vector_type(8)));

#define T_ 4

template<bool B> struct BoolT { static constexpr bool value = B; };

static __device__ __forceinline__ float b2f(unsigned short u){
  union { unsigned int i; float f; } x; x.i = ((unsigned int)u) << 16; return x.f;
}
static __device__ __forceinline__ unsigned short f2b(float f){
  unsigned int u = __float_as_uint(f);
  unsigned int r = (u + 0x7FFFu + ((u >> 16) & 1u)) >> 16;
  return (unsigned short)r;
}
static __device__ __forceinline__ float sigmoidf_(float x){ return 1.f / (1.f + expf(-x)); }

static __device__ __forceinline__ void gll16(const void* g, void* l){
  __builtin_amdgcn_global_load_lds(
      (const __attribute__((address_space(1))) void*)g,
      (__attribute__((address_space(3))) void*)l, 16, 0, 0);
}

// ------- split all weights into bf16 hi + bf16 lo (concatenated qkv|proj|fc1|fc2) -------
__global__ __launch_bounds__(256) void wsplit_kernel(const float* __restrict__ qkvw,
    const float* __restrict__ projw, const float* __restrict__ fc1w,
    const float* __restrict__ fc2w, unsigned short* __restrict__ hi,
    unsigned short* __restrict__ lo){
  int i = blockIdx.x * 256 + threadIdx.x;
  const float* src; int off;
  if (i < 786432)      { src = qkvw; off = i; }
  else if (i < 1048576){ src = projw; off = i - 786432; }
  else if (i < 2097152){ src = fc1w;  off = i - 1048576; }
  else                 { src = fc2w;  off = i - 2097152; }
  float f = src[off];
  unsigned short h = f2b(f);
  float r = f - b2f(h);
  hi[i] = h; lo[i] = f2b(r);
}

// ---- FUSED: lif(x) + depthwise 3x3 conv + residual + transpose to [T,B,N,C] f32 ----
__global__ __launch_bounds__(256) void conv_lif_kernel(const float* __restrict__ x,
    const float* __restrict__ cw, const float* __restrict__ cb,
    const float* __restrict__ lifw, float* __restrict__ xt){
  __shared__ __align__(16) float xs[16 * 260];
  __shared__ u64 sbits[16][5];
  int bb = blockIdx.x & 15, cg = blockIdx.x >> 4;
  int c0 = cg * 16;
  int tid = threadIdx.x;
  int lane = tid & 63, w = tid >> 6;
  int cl = tid & 15;
  float D = sigmoidf_(lifw[0]);
  float cwv[9];
  #pragma unroll
  for (int j = 0; j < 9; ++j) cwv[j] = cw[(c0 + cl) * 9 + j];
  float cbv = cb[c0 + cl];
  float v[16];
  #pragma unroll
  for (int k = 0; k < 16; ++k) v[k] = 0.f;

  for (int t = 0; t < T_; ++t){
    #pragma unroll
    for (int j = 0; j < 4; ++j){
      int kk = __builtin_amdgcn_readfirstlane(w + 4 * j);
      const float* grow = x + (((size_t)t * 16 + bb) * 512 + c0 + kk) * 256 + lane * 4;
      gll16(grow, &xs[kk * 260]);
    }
    __syncthreads();
    #pragma unroll
    for (int k = 0; k < 16; ++k){
      float xv = xs[k * 260 + tid];
      v[k] = v[k] + (xv - v[k]) * D;
      bool sp = v[k] >= 1.f;
      u64 bal = __ballot(sp);
      if (lane == 0) sbits[k][w] = bal;
      v[k] = sp ? 0.f : v[k];
    }
    __syncthreads();
    u64 sw0 = sbits[cl][0], sw1 = sbits[cl][1], sw2 = sbits[cl][2], sw3 = sbits[cl][3];
    #pragma unroll
    for (int i = 0; i < 16; ++i){
      int n = (tid >> 4) + 16 * i;
      int hh = n >> 4, ww = n & 15;
      float acc = cbv;
      #pragma unroll
      for (int dy = -1; dy <= 1; ++dy){
        int yy = hh + dy; if ((unsigned)yy >= 16u) continue;
        #pragma unroll
        for (int dx = -1; dx <= 1; ++dx){
          int xx = ww + dx; if ((unsigned)xx >= 16u) continue;
          int p = yy * 16 + xx;
          u64 word = (p < 64) ? sw0 : (p < 128) ? sw1 : (p < 192) ? sw2 : sw3;
          if ((word >> (p & 63)) & 1ull) acc += cwv[(dy + 1) * 3 + (dx + 1)];
        }
      }
      float xv = xs[cl * 260 + n];
      xt[(((size_t)t * 16 + bb) * 256 + n) * 512 + c0 + cl] = xv + acc;
    }
    __syncthreads();
  }
}

// --- fused LayerNorm (over C) + LIF (over T) -> bit-packed spikes [m][8] u64 ---
__global__ __launch_bounds__(256) void ln_lif_kernel(const float* __restrict__ xt,
    const float* __restrict__ g, const float* __restrict__ be,
    const float* __restrict__ lifw, int lidx, u64* __restrict__ obits){
  int bn = blockIdx.x; int tid = threadIdx.x;
  int lane = tid & 63, wid = tid >> 6;
  int c0 = tid, c1 = tid + 256;
  __shared__ float ps[8];
  float D = sigmoidf_(lifw[lidx]);
  float g0 = g[c0], g1 = g[c1];
  float b0 = be[c0], b1 = be[c1];
  float v0 = 0.f, v1 = 0.f;
  for (int t = 0; t < T_; ++t){
    size_t base = ((size_t)t * 4096 + bn) * 512;
    float x0 = xt[base + c0], x1 = xt[base + c1];
    float s = x0 + x1, q = x0 * x0 + x1 * x1;
    #pragma unroll
    for (int m = 32; m > 0; m >>= 1){
      s += __shfl_xor(s, m, 64);
      q += __shfl_xor(q, m, 64);
    }
    if (lane == 0){ ps[wid * 2] = s; ps[wid * 2 + 1] = q; }
    __syncthreads();
    float S = ps[0] + ps[2] + ps[4] + ps[6];
    float Q = ps[1] + ps[3] + ps[5] + ps[7];
    __syncthreads();
    float mean = S * (1.f / 512.f);
    float var = Q * (1.f / 512.f) - mean * mean;
    float inv = 1.f / sqrtf(var + 1e-5f);
    float y0 = (x0 - mean) * inv * g0 + b0;
    float y1 = (x1 - mean) * inv * g1 + b1;
    v0 = v0 + (y0 - v0) * D; bool s0 = v0 >= 1.f;
    v1 = v1 + (y1 - v1) * D; bool s1 = v1 >= 1.f;
    u64 bal0 = __ballot(s0);
    u64 bal1 = __ballot(s1);
    if (lane == 0){
      size_t rb = ((size_t)t * 4096 + bn) * 8;
      obits[rb + wid] = bal0;
      obits[rb + 4 + wid] = bal1;
    }
    v0 = s0 ? 0.f : v0; v1 = s1 ? 0.f : v1;
  }
}

// ------- LIF over [16384,512] f32 pre-acts -> bit-packed spikes [m][8] u64 -------
__global__ __launch_bounds__(256) void lif_bits_kernel(const float* __restrict__ in,
    u64* __restrict__ bits, const float* __restrict__ lifw, int lidx){
  int tid = blockIdx.x * 256 + threadIdx.x;
  int j = tid & 511; int bn = tid >> 9;
  float D = sigmoidf_(lifw[lidx]);
  float v = 0.f;
  #pragma unroll
  for (int t = 0; t < T_; ++t){
    int m = t * 4096 + bn;
    float xv = in[(size_t)m * 512 + j];
    v = v + (xv - v) * D;
    bool sp = v >= 1.f;
    u64 bal = __ballot(sp);
    if ((threadIdx.x & 63) == 0) bits[(size_t)m * 8 + (j >> 6)] = bal;
    v = sp ? 0.f : v;
  }
}

// ---- NT GEMM: A = bit-packed spikes (nibble-LUT expand), split-bf16 weights ----
// R8 memory schedule (wave-local staging, counted vmcnt(4), chunk restage barriers)
// with a FULLY STATIC K-loop (R8 lesson: the plateau's residual is dynamic loop
// machinery -- runtime K/mode/ars, per-iter branch/flag/cur math, 64-bit address
// recompute). Template<GROUPS,K,MODE,ARS>: dynamic outer chunk loop (<=4 trips) x
// unrolled 8-iter body with compile-time LAST tag => cur=i&1, wl=i, vmcnt select,
// restage and stage-skip conditions all static; gll16/ds offsets fold to imms.
// mode 0: xtio[g,col] += acc + bias            (GROUPS=2)
// mode 1: LIF(2+part) -> outBits (qkv)         (GROUPS=1)
// mode 2: LIF(lidx)+bias -> outBits (fc1)      (GROUPS=1)
// mode 3: acc+bias+xtio -> transposed outF     (GROUPS=2)
template<int GROUPS, int K, int MODE, int ARS>
__global__ __launch_bounds__(GROUPS * 256, 4) void gemm_fused(
    const u64* __restrict__ Abits,
    const unsigned short* __restrict__ Whi, const unsigned short* __restrict__ Wlo, int ldw,
    const float* __restrict__ bias,
    float* __restrict__ xtio, float* __restrict__ outF,
    u64* __restrict__ outBits,
    const float* __restrict__ lifw, int lidx){
  constexpr int NT  = GROUPS * 256;
  constexpr int KH  = K / GROUPS;     // per-group K
  constexpr int NCH = KH / 256;       // 256-K chunks per group (proj:1, qkv/fc1:2, fc2:4)
  extern __shared__ __align__(16) char smemraw[];
  // layout: Bh[GROUPS][2][4096]us | Bl[GROUPS][2][4096]us | Alds[GROUPS][8][128]u32 | tab[16]u64
  unsigned short* Bh = (unsigned short*)smemraw;
  unsigned short* Bl = (unsigned short*)(smemraw + GROUPS * 16384);
  u32* Alds = (u32*)(smemraw + GROUPS * 32768);
  u64* tab  = (u64*)(smemraw + GROUPS * 32768 + GROUPS * 4096);
  int bn0 = blockIdx.x * 32;
  int n0  = blockIdx.y * 128;
  int tid = threadIdx.x, lane = tid & 63, wid = tid >> 6;
  int grp = (GROUPS == 2) ? (wid >> 2) : 0;
  int wv  = wid & 3;
  int wn = wv * 32;
  int lm = lane & 15, quad = lane >> 4;
  int qs = quad * 8;
  int swz = ((lane & 3) ^ ((lane >> 3) & 3)) * 8;
  int kbase = grp * KH;
  // wave-own staging rows: [wn, wn+32). Row for this lane: wn + lane>>2 (+16 for p*1)
  int rW = wn + (lane >> 2);
  const unsigned short* pH0 = Whi + (size_t)(n0 + rW) * ldw + swz + kbase;
  const unsigned short* pH1 = pH0 + (size_t)16 * ldw;
  const unsigned short* pL0 = Wlo + (size_t)(n0 + rW) * ldw + swz + kbase;
  const unsigned short* pL1 = pL0 + (size_t)16 * ldw;
  int gb  = __builtin_amdgcn_readfirstlane(grp * 8192);       // group's ushort base in Bh/Bl
  int wb  = __builtin_amdgcn_readfirstlane(grp * 8192 + wv * 1024);
  int sx = (quad ^ ((lm >> 1) & 3)) << 3;

  // stage one 256-K chunk of A-bits per group (4 u64 x 128 rows x GROUPS), word-major
  auto stageA = [&](int c){
    #pragma unroll
    for (int i = 0; i < 2; ++i){
      int idx = tid + i * NT;
      int r = idx & 127;
      int q = idx >> 7;            // 0..GROUPS*4-1
      int g = q >> 2, w = q & 3;   // group, u64-within-chunk
      size_t grow = (size_t)((r >> 5) * 4096 + bn0 + (r & 31));
      u64 vb = Abits[grow * ARS + (size_t)g * (KH >> 6) + c * 4 + w];
      Alds[g * 1024 + (2 * w) * 128 + r]     = (u32)vb;
      Alds[g * 1024 + (2 * w + 1) * 128 + r] = (u32)(vb >> 32);
    }
  };
  // wave-local: stage this wave's own 32 hi/lo B rows for one 32-K tile of its group
  auto stageB = [&](int buf, int kb){
    int bo = wb + (buf << 12);
    gll16(pH0 + kb, Bh + bo);
    gll16(pH1 + kb, Bh + bo + 512);
    gll16(pL0 + kb, Bl + bo);
    gll16(pL1 + kb, Bl + bo + 512);
  };

  // nibble -> 4 bf16 LUT (entry n on its own bank pair; reads broadcast/conflict-free)
  if (tid < 16){
    u64 e = 0;
    #pragma unroll
    for (int j = 0; j < 4; ++j) if ((tid >> j) & 1) e |= 0x3F80ull << (16 * j);
    tab[tid] = e;
  }
  stageA(0);
  stageB(0, 0);
  stageB(1, 32);
  __syncthreads();  // one-time: A chunk + tab visible; tiles 0,1 drained

  floatx4 acc[8][2];
  #pragma unroll
  for (int i = 0; i < 8; ++i)
    #pragma unroll
    for (int j = 0; j < 2; ++j){ acc[i][j][0]=0.f; acc[i][j][1]=0.f; acc[i][j][2]=0.f; acc[i][j][3]=0.f; }

  // one 256-K chunk = 8 statically-unrolled 32-K iterations
  auto chunkbody = [&](int ch, auto lastc){
    constexpr bool LAST = decltype(lastc)::value;
    if (ch != 0){
      // chunk boundary: rendezvous (all groups at same trip count), restage A.
      // Costs a vmcnt drain; only NCH-1 times per block (<=3 for fc2).
      __syncthreads();
      stageA(ch);
      __syncthreads();
    }
    #pragma unroll
    for (int i = 0; i < 8; ++i){
      const int kb = ch * 256 + i * 32;
      const int wl = i;            // static
      const int cur = i & 1;       // static (8 flips per chunk -> parity preserved)
      // steady state: 8 outstanding gll16 (tiles k, k+1); vmcnt(4) forces tile k.
      if (LAST && i == 7) asm volatile("s_waitcnt vmcnt(0)" ::: "memory");
      else                asm volatile("s_waitcnt vmcnt(4)" ::: "memory");
      __builtin_amdgcn_sched_barrier(0);
      int bo = gb + (cur << 12);
      short8 bh[2], bl[2];
      #pragma unroll
      for (int in = 0; in < 2; ++in){
        bh[in] = *(const short8*)(&Bh[bo + (wn + in * 16 + lm) * 32 + sx]);
        bl[in] = *(const short8*)(&Bl[bo + (wn + in * 16 + lm) * 32 + sx]);
      }
      __builtin_amdgcn_s_setprio(1);
      #pragma unroll
      for (int im = 0; im < 8; ++im){
        u32 wv32 = Alds[grp * 1024 + wl * 128 + im * 16 + lm];
        u32 by = wv32 >> qs;
        union { u64 d[2]; short8 s; } c;
        c.d[0] = tab[by & 15u];
        c.d[1] = tab[(by >> 4) & 15u];
        acc[im][0] = __builtin_amdgcn_mfma_f32_16x16x32_bf16(c.s, bh[0], acc[im][0], 0, 0, 0);
        acc[im][1] = __builtin_amdgcn_mfma_f32_16x16x32_bf16(c.s, bh[1], acc[im][1], 0, 0, 0);
        acc[im][0] = __builtin_amdgcn_mfma_f32_16x16x32_bf16(c.s, bl[0], acc[im][0], 0, 0, 0);
        acc[im][1] = __builtin_amdgcn_mfma_f32_16x16x32_bf16(c.s, bl[1], acc[im][1], 0, 0, 0);
      }
      __builtin_amdgcn_s_setprio(0);
      __builtin_amdgcn_sched_barrier(0);
      // refill own buffer with tile k+2 (wave-local; MFMAs consumed buf cur already).
      // Skip only the final two iterations of the last chunk.
      if (!(LAST && i >= 6)) stageB(cur, kb + 64);
    }
  };
  for (int ch = 0; ch < NCH - 1; ++ch) chunkbody(ch, BoolT<false>{});
  chunkbody(NCH - 1, BoolT<true>{});

  if constexpr (MODE == 0 || MODE == 3){
    float* X = (float*)smemraw;   // [128][132] f32 exchange (GROUPS=2), reuses B region
    if constexpr (GROUPS == 2){
      __syncthreads();            // all waves done with B/A LDS
      if (grp == 1){
        #pragma unroll
        for (int im = 0; im < 8; ++im){
          int row0 = im * 16 + quad * 4;
          #pragma unroll
          for (int in = 0; in < 2; ++in){
            int cl_ = wn + in * 16 + lm;
            #pragma unroll
            for (int r = 0; r < 4; ++r)
              X[(row0 + r) * 132 + cl_] = acc[im][in][r];
          }
        }
      }
      __syncthreads();
      if (grp == 1) return;
    }
    #pragma unroll
    for (int im = 0; im < 8; ++im){
      int row0 = im * 16 + quad * 4;
      #pragma unroll
      for (int in = 0; in < 2; ++in){
        int col = n0 + wn + in * 16 + lm;
        float bv = bias ? bias[col] : 0.f;
        #pragma unroll
        for (int r = 0; r < 4; ++r){
          int row = row0 + r;
          int t = row >> 5; int bq = bn0 + (row & 31);
          size_t gg = (size_t)t * 4096 + bq;
          float vv = acc[im][in][r] + bv + xtio[gg * 512 + col];
          if constexpr (GROUPS == 2) vv += X[row * 132 + wn + in * 16 + lm];
          if constexpr (MODE == 0){
            xtio[gg * 512 + col] = vv;
          } else {
            outF[(((size_t)t * 16 + (bq >> 8)) * 512 + col) * 256 + (bq & 255)] = vv;
          }
        }
      }
    }
    return;
  }

  if constexpr (MODE == 1 || MODE == 2){
    // modes 1/2 (GROUPS=1): pure-register LIF (all 4 timesteps of a token in one
    // lane), ballot -> bit-packed output. token A = quad*4+r (im=2t), B = 16+quad*4+r
    __syncthreads();  // waves free-run in the loop; all must finish Alds reads before reuse
    u32* bits32 = (u32*)(smemraw + 32768);         // [128][4] u32, reuses Alds region
    u64* ob; int obrs, obwb;
    if constexpr (MODE == 1){ ob = outBits + (size_t)(n0 >> 9) * 131072; obrs = 8; obwb = (n0 & 511) >> 6; }
    else                    { ob = outBits; obrs = 32; obwb = n0 >> 6; }
    float D = sigmoidf_(lifw[MODE == 1 ? (2 + (n0 >> 9)) : lidx]);
    float bv0 = bias ? bias[n0 + wn + lm] : 0.f;
    float bv1 = bias ? bias[n0 + wn + 16 + lm] : 0.f;
    #pragma unroll
    for (int r = 0; r < 4; ++r){
      float vA0 = 0.f, vA1 = 0.f, vB0 = 0.f, vB1 = 0.f;
      #pragma unroll
      for (int t = 0; t < 4; ++t){
        float pA0 = acc[2*t][0][r] + bv0;   vA0 += (pA0 - vA0) * D; bool sA0 = vA0 >= 1.f; vA0 = sA0 ? 0.f : vA0;
        float pA1 = acc[2*t][1][r] + bv1;   vA1 += (pA1 - vA1) * D; bool sA1 = vA1 >= 1.f; vA1 = sA1 ? 0.f : vA1;
        float pB0 = acc[2*t+1][0][r] + bv0; vB0 += (pB0 - vB0) * D; bool sB0 = vB0 >= 1.f; vB0 = sB0 ? 0.f : vB0;
        float pB1 = acc[2*t+1][1][r] + bv1; vB1 += (pB1 - vB1) * D; bool sB1 = vB1 >= 1.f; vB1 = sB1 ? 0.f : vB1;
        u64 balA0 = __ballot(sA0), balA1 = __ballot(sA1);
        u64 balB0 = __ballot(sB0), balB1 = __ballot(sB1);
        if (lane < 4){
          int q = lane;
          u32 wA = (u32)((balA0 >> (16*q)) & 0xFFFFull) | ((u32)((balA1 >> (16*q)) & 0xFFFFull) << 16);
          u32 wB = (u32)((balB0 >> (16*q)) & 0xFFFFull) | ((u32)((balB1 >> (16*q)) & 0xFFFFull) << 16);
          bits32[(t * 32 + q * 4 + r) * 4 + wid]      = wA;
          bits32[(t * 32 + 16 + q * 4 + r) * 4 + wid] = wB;
        }
      }
    }
    __syncthreads();
    {
      int t = tid >> 6, bnl = (tid >> 1) & 31, j = tid & 1;
      size_t g = (size_t)t * 4096 + bn0 + bnl;
      int idx = (t * 32 + bnl) * 4 + 2 * j;
      u64 wv64 = (u64)bits32[idx] | ((u64)bits32[idx + 1] << 32);
      ob[g * obrs + obwb + j] = wv64;
    }
  }
}

// ---- attention pre-acts per (t,b,h): a = (q @ kvm) * 0.125 via MFMA, kvm by popcount ----
__global__ __launch_bounds__(256) void attn_a_kernel(const u64* __restrict__ bits,
    float* __restrict__ aout){
  int tbh = blockIdx.x;
  int h = tbh & 7, b = (tbh >> 3) & 15, t = tbh >> 7;
  int m0 = t * 4096 + b * 256;
  int tid = threadIdx.x, lane = tid & 63, wid = tid >> 6;
  __shared__ u64 QW[256], KW[256], VW[256];
  __shared__ u64 kbt[64][4], vbt[64][4];
  __shared__ __align__(16) unsigned short Bs[64 * 72];
  {
    size_t base = (size_t)(m0 + tid) * 8 + h;
    QW[tid] = bits[base];
    KW[tid] = bits[131072 + base];
    VW[tid] = bits[262144 + base];
  }
  __syncthreads();
  {
    int i = tid & 63, w = tid >> 6;
    const u64* kwp = &KW[w * 64];
    const u64* vwp = &VW[w * 64];
    u64 bk = 0, bv = 0;
    for (int nn = 0; nn < 64; ++nn){
      bk |= ((kwp[nn] >> i) & 1ull) << nn;
      bv |= ((vwp[nn] >> i) & 1ull) << nn;
    }
    kbt[i][w] = bk; vbt[i][w] = bv;
  }
  __syncthreads();
  #pragma unroll
  for (int e = 0; e < 16; ++e){
    int idx = tid * 16 + e;
    int i = idx >> 6, j = idx & 63;
    int cnt = __popcll(kbt[i][0] & vbt[j][0]) + __popcll(kbt[i][1] & vbt[j][1])
            + __popcll(kbt[i][2] & vbt[j][2]) + __popcll(kbt[i][3] & vbt[j][3]);
    Bs[j * 72 + i] = f2b((float)cnt);
  }
  __syncthreads();
  int lm = lane & 15, quad = lane >> 4;
  int wm = wid * 64;
  u64 qw[4];
  #pragma unroll
  for (int im = 0; im < 4; ++im) qw[im] = QW[wm + im * 16 + lm];
  floatx4 acc[4][4];
  #pragma unroll
  for (int i = 0; i < 4; ++i)
    #pragma unroll
    for (int j = 0; j < 4; ++j){ acc[i][j][0]=0.f; acc[i][j][1]=0.f; acc[i][j][2]=0.f; acc[i][j][3]=0.f; }
  #pragma unroll
  for (int kb = 0; kb < 64; kb += 32){
    short8 af[4], bf[4];
    #pragma unroll
    for (int im = 0; im < 4; ++im){
      u32 byte = (u32)(qw[im] >> (kb + quad * 8)) & 0xFFu;
      union { u32 u[4]; short8 s; } c;
      c.u[0] = ((byte & 1u)        | ((byte & 2u) << 15))        * 0x3F80u;
      c.u[1] = (((byte >> 2) & 1u) | (((byte >> 3) & 1u) << 16)) * 0x3F80u;
      c.u[2] = (((byte >> 4) & 1u) | (((byte >> 5) & 1u) << 16)) * 0x3F80u;
      c.u[3] = (((byte >> 6) & 1u) | (((byte >> 7) & 1u) << 16)) * 0x3F80u;
      af[im] = c.s;
    }
    #pragma unroll
    for (int in = 0; in < 4; ++in)
      bf[in] = *(const short8*)(&Bs[(in * 16 + lm) * 72 + kb + quad * 8]);
    #pragma unroll
    for (int im = 0; im < 4; ++im)
      #pragma unroll
      for (int in = 0; in < 4; ++in)
        acc[im][in] = __builtin_amdgcn_mfma_f32_16x16x32_bf16(af[im], bf[in], acc[im][in], 0, 0, 0);
  }
  float* ob = aout + (size_t)m0 * 512 + h * 64;
  #pragma unroll
  for (int im = 0; im < 4; ++im){
    int nr0 = wm + im * 16 + quad * 4;
    #pragma unroll
    for (int in = 0; in < 4; ++in){
      int j = in * 16 + lm;
      #pragma unroll
      for (int r = 0; r < 4; ++r)
        ob[(size_t)(nr0 + r) * 512 + j] = acc[im][in][r] * 0.125f;
    }
  }
}

extern "C" void kernel_launch(void* const* d_in, const int* in_sizes, int n_in,
                              void* d_out, int out_size, void* d_ws, size_t ws_size,
                              hipStream_t stream){
  const float* x     = (const float*)d_in[0];
  const float* convw = (const float*)d_in[1];
  const float* convb = (const float*)d_in[2];
  const float* ln1g  = (const float*)d_in[3];
  const float* ln1b  = (const float*)d_in[4];
  const float* qkvw  = (const float*)d_in[5];
  const float* projw = (const float*)d_in[6];
  const float* projb = (const float*)d_in[7];
  const float* ln2g  = (const float*)d_in[8];
  const float* ln2b  = (const float*)d_in[9];
  const float* fc1w  = (const float*)d_in[10];
  const float* fc1b  = (const float*)d_in[11];
  const float* fc2w  = (const float*)d_in[12];
  const float* fc2b  = (const float*)d_in[13];
  const float* lifw  = (const float*)d_in[14];
  float* outp = (float*)d_out;

  // workspace layout (~89 MB)
  char* wsb = (char*)d_ws;
  float* XT           = (float*)wsb;                           // [16384,512] f32  33.5 MB
  float* AF32         = (float*)(wsb + 33554432);              // [16384,512] f32  33.5 MB
  unsigned short* WHI = (unsigned short*)(wsb + 67108864);     //  6.3 MB
  unsigned short* WLO = (unsigned short*)(wsb + 73400320);     //  6.3 MB
  u64* QBITS          = (u64*)(wsb + 79691776);                // [3,16384,8]  3.1 MB
  u64* H12            = (u64*)(wsb + 82837504);                // [16384,8]    1.0 MB
  u64* ASB            = (u64*)(wsb + 83886080);                // [16384,8]    1.0 MB
  u64* HBITS          = (u64*)(wsb + 84934656);                // [16384,32]   4.2 MB
  const int OFF_QKV = 0, OFF_PROJ = 786432, OFF_FC1 = 1048576, OFF_FC2 = 2097152;
  const int LDS1 = 36992;  // 32K (B dbuf) + 4K (A chunk) + 128 (LUT) -> 4 blocks/CU
  const int LDS2 = 73856;  // 64K (2 groups B) + 8K (A chunks) + 128 -> 2 blocks/CU

  wsplit_kernel<<<12288, 256, 0, stream>>>(qkvw, projw, fc1w, fc2w, WHI, WLO);
  conv_lif_kernel<<<512, 256, 0, stream>>>(x, convw, convb, lifw, XT);
  // h1 bits
  ln_lif_kernel<<<4096, 256, 0, stream>>>(XT, ln1g, ln1b, lifw, 1, H12);
  // qkv GEMM + LIF -> bit-packed q,k,v
  gemm_fused<1, 512, 1, 8><<<dim3(128, 12), 256, LDS1, stream>>>(H12,
      WHI + OFF_QKV, WLO + OFF_QKV, 512, nullptr,
      nullptr, nullptr, QBITS, lifw, 0);
  // attention pre-acts
  attn_a_kernel<<<512, 256, 0, stream>>>(QBITS, AF32);
  // a_s bits
  lif_bits_kernel<<<8192, 256, 0, stream>>>(AF32, ASB, lifw, 5);
  // xt += a_s @ proj^T + proj_b   (in-block K-split, 512 threads)
  gemm_fused<2, 512, 0, 8><<<dim3(128, 4), 512, LDS2, stream>>>(ASB,
      WHI + OFF_PROJ, WLO + OFF_PROJ, 512, projb,
      XT, nullptr, nullptr, lifw, 0);
  // h2 bits
  ln_lif_kernel<<<4096, 256, 0, stream>>>(XT, ln2g, ln2b, lifw, 6, H12);
  // fc1 (merged, N=2048) + LIF -> HBITS
  gemm_fused<1, 512, 2, 8><<<dim3(128, 16), 256, LDS1, stream>>>(H12,
      WHI + OFF_FC1, WLO + OFF_FC1, 512, fc1b,
      nullptr, nullptr, HBITS, lifw, 7);
  // fc2 (merged, K=2048) + residual -> final transposed output (in-block K-split)
  gemm_fused<2, 2048, 3, 32><<<dim3(128, 4), 512, LDS2, stream>>>(HBITS,
      WHI + OFF_FC2, WLO + OFF_FC2, 2048, fc2b,
      XT, outp, nullptr, lifw, 0);
}

// Round 10
// 368.813 us; speedup vs baseline: 1.4008x; 1.4008x over previous
//
#include <hip/hip_runtime.h>

typedef unsigned long long u64;
typedef unsigned int u32;
typedef float  floatx4 __attribute__((ext_vector_type(4)));
typedef short  short8  __attribute__((ext_vector_type(8)));

#define T_ 4

static __device__ __forceinline__ float b2f(unsigned short u){
  union { unsigned int i; float f; } x; x.i = ((unsigned int)u) << 16; return x.f;
}
static __device__ __forceinline__ unsigned short f2b(float f){
  unsigned int u = __float_as_uint(f);
  unsigned int r = (u + 0x7FFFu + ((u >> 16) & 1u)) >> 16;
  return (unsigned short)r;
}
static __device__ __forceinline__ float sigmoidf_(float x){ return 1.f / (1.f + expf(-x)); }

static __device__ __forceinline__ void gll16(const void* g, void* l){
  __builtin_amdgcn_global_load_lds(
      (const __attribute__((address_space(1))) void*)g,
      (__attribute__((address_space(3))) void*)l, 16, 0, 0);
}

// ------- split all weights into bf16 hi + bf16 lo (concatenated qkv|proj|fc1|fc2) -------
__global__ __launch_bounds__(256) void wsplit_kernel(const float* __restrict__ qkvw,
    const float* __restrict__ projw, const float* __restrict__ fc1w,
    const float* __restrict__ fc2w, unsigned short* __restrict__ hi,
    unsigned short* __restrict__ lo){
  int i = blockIdx.x * 256 + threadIdx.x;
  const float* src; int off;
  if (i < 786432)      { src = qkvw; off = i; }
  else if (i < 1048576){ src = projw; off = i - 786432; }
  else if (i < 2097152){ src = fc1w;  off = i - 1048576; }
  else                 { src = fc2w;  off = i - 2097152; }
  float f = src[off];
  unsigned short h = f2b(f);
  float r = f - b2f(h);
  hi[i] = h; lo[i] = f2b(r);
}

// ---- FUSED: lif(x) + depthwise 3x3 conv + residual + transpose to [T,B,N,C] f32 ----
__global__ __launch_bounds__(256) void conv_lif_kernel(const float* __restrict__ x,
    const float* __restrict__ cw, const float* __restrict__ cb,
    const float* __restrict__ lifw, float* __restrict__ xt){
  __shared__ __align__(16) float xs[16 * 260];
  __shared__ u64 sbits[16][5];
  int bb = blockIdx.x & 15, cg = blockIdx.x >> 4;
  int c0 = cg * 16;
  int tid = threadIdx.x;
  int lane = tid & 63, w = tid >> 6;
  int cl = tid & 15;
  float D = sigmoidf_(lifw[0]);
  float cwv[9];
  #pragma unroll
  for (int j = 0; j < 9; ++j) cwv[j] = cw[(c0 + cl) * 9 + j];
  float cbv = cb[c0 + cl];
  float v[16];
  #pragma unroll
  for (int k = 0; k < 16; ++k) v[k] = 0.f;

  for (int t = 0; t < T_; ++t){
    #pragma unroll
    for (int j = 0; j < 4; ++j){
      int kk = __builtin_amdgcn_readfirstlane(w + 4 * j);
      const float* grow = x + (((size_t)t * 16 + bb) * 512 + c0 + kk) * 256 + lane * 4;
      gll16(grow, &xs[kk * 260]);
    }
    __syncthreads();
    #pragma unroll
    for (int k = 0; k < 16; ++k){
      float xv = xs[k * 260 + tid];
      v[k] = v[k] + (xv - v[k]) * D;
      bool sp = v[k] >= 1.f;
      u64 bal = __ballot(sp);
      if (lane == 0) sbits[k][w] = bal;
      v[k] = sp ? 0.f : v[k];
    }
    __syncthreads();
    u64 sw0 = sbits[cl][0], sw1 = sbits[cl][1], sw2 = sbits[cl][2], sw3 = sbits[cl][3];
    #pragma unroll
    for (int i = 0; i < 16; ++i){
      int n = (tid >> 4) + 16 * i;
      int hh = n >> 4, ww = n & 15;
      float acc = cbv;
      #pragma unroll
      for (int dy = -1; dy <= 1; ++dy){
        int yy = hh + dy; if ((unsigned)yy >= 16u) continue;
        #pragma unroll
        for (int dx = -1; dx <= 1; ++dx){
          int xx = ww + dx; if ((unsigned)xx >= 16u) continue;
          int p = yy * 16 + xx;
          u64 word = (p < 64) ? sw0 : (p < 128) ? sw1 : (p < 192) ? sw2 : sw3;
          if ((word >> (p & 63)) & 1ull) acc += cwv[(dy + 1) * 3 + (dx + 1)];
        }
      }
      float xv = xs[cl * 260 + n];
      xt[(((size_t)t * 16 + bb) * 256 + n) * 512 + c0 + cl] = xv + acc;
    }
    __syncthreads();
  }
}

// --- fused LayerNorm (over C) + LIF (over T) -> bit-packed spikes [m][8] u64 ---
__global__ __launch_bounds__(256) void ln_lif_kernel(const float* __restrict__ xt,
    const float* __restrict__ g, const float* __restrict__ be,
    const float* __restrict__ lifw, int lidx, u64* __restrict__ obits){
  int bn = blockIdx.x; int tid = threadIdx.x;
  int lane = tid & 63, wid = tid >> 6;
  int c0 = tid, c1 = tid + 256;
  __shared__ float ps[8];
  float D = sigmoidf_(lifw[lidx]);
  float g0 = g[c0], g1 = g[c1];
  float b0 = be[c0], b1 = be[c1];
  float v0 = 0.f, v1 = 0.f;
  for (int t = 0; t < T_; ++t){
    size_t base = ((size_t)t * 4096 + bn) * 512;
    float x0 = xt[base + c0], x1 = xt[base + c1];
    float s = x0 + x1, q = x0 * x0 + x1 * x1;
    #pragma unroll
    for (int m = 32; m > 0; m >>= 1){
      s += __shfl_xor(s, m, 64);
      q += __shfl_xor(q, m, 64);
    }
    if (lane == 0){ ps[wid * 2] = s; ps[wid * 2 + 1] = q; }
    __syncthreads();
    float S = ps[0] + ps[2] + ps[4] + ps[6];
    float Q = ps[1] + ps[3] + ps[5] + ps[7];
    __syncthreads();
    float mean = S * (1.f / 512.f);
    float var = Q * (1.f / 512.f) - mean * mean;
    float inv = 1.f / sqrtf(var + 1e-5f);
    float y0 = (x0 - mean) * inv * g0 + b0;
    float y1 = (x1 - mean) * inv * g1 + b1;
    v0 = v0 + (y0 - v0) * D; bool s0 = v0 >= 1.f;
    v1 = v1 + (y1 - v1) * D; bool s1 = v1 >= 1.f;
    u64 bal0 = __ballot(s0);
    u64 bal1 = __ballot(s1);
    if (lane == 0){
      size_t rb = ((size_t)t * 4096 + bn) * 8;
      obits[rb + wid] = bal0;
      obits[rb + 4 + wid] = bal1;
    }
    v0 = s0 ? 0.f : v0; v1 = s1 ? 0.f : v1;
  }
}

// ------- LIF over [16384,512] f32 pre-acts -> bit-packed spikes [m][8] u64 -------
__global__ __launch_bounds__(256) void lif_bits_kernel(const float* __restrict__ in,
    u64* __restrict__ bits, const float* __restrict__ lifw, int lidx){
  int tid = blockIdx.x * 256 + threadIdx.x;
  int j = tid & 511; int bn = tid >> 9;
  float D = sigmoidf_(lifw[lidx]);
  float v = 0.f;
  #pragma unroll
  for (int t = 0; t < T_; ++t){
    int m = t * 4096 + bn;
    float xv = in[(size_t)m * 512 + j];
    v = v + (xv - v) * D;
    bool sp = v >= 1.f;
    u64 bal = __ballot(sp);
    if ((threadIdx.x & 63) == 0) bits[(size_t)m * 8 + (j >> 6)] = bal;
    v = sp ? 0.f : v;
  }
}

// ---- NT GEMM: A = bit-packed spikes (nibble-LUT expand), split-bf16 weights ----
// R8 structure EXACTLY (best measured 374.85us: wave-local staging, counted
// vmcnt(4), chunk restage barriers, depth-2 tab hoist, dynamic K-loop, VGPR 64,
// 0 spills, 0 conflicts) minus the two in-loop sched_barrier(0) pins (m137/m141:
// order-pinning defeats the scheduler; ds_reads are ordered by the vmcnt asm's
// "memory" clobber, and gll16-vs-ds_read aliasing can't be disproven, so
// correctness is unchanged). R7/R9 lesson: NO added live state -- this kernel
// sits at the 4-waves/SIMD register ceiling (acc=64 AGPRs).
// mode 0: xtio[g,col] += acc + bias            (GROUPS=2)
// mode 1: LIF(2+part) -> outBits (qkv)         (GROUPS=1)
// mode 2: LIF(lidx)+bias -> outBits (fc1)      (GROUPS=1)
// mode 3: acc+bias+xtio -> transposed outF     (GROUPS=2)
template<int GROUPS>
__global__ __launch_bounds__(GROUPS * 256, 4) void gemm_fused(
    const u64* __restrict__ Abits, int ars,
    const unsigned short* __restrict__ Whi, const unsigned short* __restrict__ Wlo, int ldw,
    const float* __restrict__ bias,
    float* __restrict__ xtio, float* __restrict__ outF,
    u64* __restrict__ outBits,
    int K, int mode, const float* __restrict__ lifw, int lidx){
  constexpr int NT = GROUPS * 256;
  extern __shared__ __align__(16) char smemraw[];
  // layout: Bh[GROUPS][2][4096]us | Bl[GROUPS][2][4096]us | Alds[GROUPS][8][128]u32 | tab[16]u64
  unsigned short* Bh = (unsigned short*)smemraw;
  unsigned short* Bl = (unsigned short*)(smemraw + GROUPS * 16384);
  u32* Alds = (u32*)(smemraw + GROUPS * 32768);
  u64* tab  = (u64*)(smemraw + GROUPS * 32768 + GROUPS * 4096);
  const int KH = K / GROUPS;
  int bn0 = blockIdx.x * 32;
  int n0  = blockIdx.y * 128;
  int tid = threadIdx.x, lane = tid & 63, wid = tid >> 6;
  int grp = (GROUPS == 2) ? (wid >> 2) : 0;
  int wv  = wid & 3;
  int wn = wv * 32;
  int lm = lane & 15, quad = lane >> 4;
  int qs = quad * 8;
  int swz = ((lane & 3) ^ ((lane >> 3) & 3)) * 8;
  int kbase = grp * KH;
  // wave-own staging rows: [wn, wn+32). Row for this lane: wn + lane>>2 (+16 for p*1)
  int rW = wn + (lane >> 2);
  const unsigned short* pH0 = Whi + (size_t)(n0 + rW) * ldw + swz + kbase;
  const unsigned short* pH1 = pH0 + (size_t)16 * ldw;
  const unsigned short* pL0 = Wlo + (size_t)(n0 + rW) * ldw + swz + kbase;
  const unsigned short* pL1 = pL0 + (size_t)16 * ldw;
  int gb  = __builtin_amdgcn_readfirstlane(grp * 8192);       // group's ushort base in Bh/Bl
  int wb  = __builtin_amdgcn_readfirstlane(grp * 8192 + wv * 1024);
  int sx = (quad ^ ((lm >> 1) & 3)) << 3;

  // stage one 256-K chunk of A-bits per group (4 u64 x 128 rows x GROUPS), word-major
  auto stageA = [&](int c){
    #pragma unroll
    for (int i = 0; i < 2; ++i){
      int idx = tid + i * NT;
      int r = idx & 127;
      int q = idx >> 7;            // 0..GROUPS*4-1
      int g = q >> 2, w = q & 3;   // group, u64-within-chunk
      size_t grow = (size_t)((r >> 5) * 4096 + bn0 + (r & 31));
      u64 vb = Abits[grow * ars + (size_t)g * (KH >> 6) + c * 4 + w];
      Alds[g * 1024 + (2 * w) * 128 + r]     = (u32)vb;
      Alds[g * 1024 + (2 * w + 1) * 128 + r] = (u32)(vb >> 32);
    }
  };
  // wave-local: stage this wave's own 32 hi/lo B rows for one 32-K tile of its group
  auto stageB = [&](int buf, int kb){
    int bo = wb + (buf << 12);
    gll16(pH0 + kb, Bh + bo);
    gll16(pH1 + kb, Bh + bo + 512);
    gll16(pL0 + kb, Bl + bo);
    gll16(pL1 + kb, Bl + bo + 512);
  };

  u32 aw[8];   // A-words for the CURRENT iteration (prefetched one iter ahead)
  auto loadA = [&](int wl){
    #pragma unroll
    for (int im = 0; im < 8; ++im)
      aw[im] = Alds[grp * 1024 + wl * 128 + im * 16 + lm];
  };

  // nibble -> 4 bf16 LUT (entry n on its own bank pair; reads broadcast/conflict-free)
  if (tid < 16){
    u64 e = 0;
    #pragma unroll
    for (int j = 0; j < 4; ++j) if ((tid >> j) & 1) e |= 0x3F80ull << (16 * j);
    tab[tid] = e;
  }
  stageA(0);
  stageB(0, 0);
  stageB(1, 32);
  __syncthreads();  // one-time: A chunk + tab visible; tiles 0,1 drained
  loadA(0);

  floatx4 acc[8][2];
  #pragma unroll
  for (int i = 0; i < 8; ++i)
    #pragma unroll
    for (int j = 0; j < 2; ++j){ acc[i][j][0]=0.f; acc[i][j][1]=0.f; acc[i][j][2]=0.f; acc[i][j][3]=0.f; }

  int cur = 0;
  for (int kb = 0; kb < KH; kb += 32){
    if (kb && (kb & 255) == 0){
      // chunk boundary: rendezvous (all groups at same trip count), restage A.
      __syncthreads();
      stageA(kb >> 8);
      __syncthreads();
      loadA((kb >> 5) & 7);
    }
    // depth-2 hoist: expand im=0,1 BEFORE the vmcnt wait (tab latency hides under it)
    union { u64 d[2]; short8 s; } c0, c1;
    {
      u32 by0 = aw[0] >> qs;
      c0.d[0] = tab[by0 & 15u];
      c0.d[1] = tab[(by0 >> 4) & 15u];
      u32 by1 = aw[1] >> qs;
      c1.d[0] = tab[by1 & 15u];
      c1.d[1] = tab[(by1 >> 4) & 15u];
    }
    // steady state: 8 outstanding gll16 (tiles k, k+1); vmcnt(4) forces tile k.
    if (kb + 32 < KH) asm volatile("s_waitcnt vmcnt(4)" ::: "memory");
    else              asm volatile("s_waitcnt vmcnt(0)" ::: "memory");
    int bo = gb + (cur << 12);
    short8 bh[2], bl[2];
    #pragma unroll
    for (int in = 0; in < 2; ++in){
      bh[in] = *(const short8*)(&Bh[bo + (wn + in * 16 + lm) * 32 + sx]);
      bl[in] = *(const short8*)(&Bl[bo + (wn + in * 16 + lm) * 32 + sx]);
    }
    __builtin_amdgcn_s_setprio(1);
    // im=0,1 from pre-expanded fragments
    acc[0][0] = __builtin_amdgcn_mfma_f32_16x16x32_bf16(c0.s, bh[0], acc[0][0], 0, 0, 0);
    acc[0][1] = __builtin_amdgcn_mfma_f32_16x16x32_bf16(c0.s, bh[1], acc[0][1], 0, 0, 0);
    acc[0][0] = __builtin_amdgcn_mfma_f32_16x16x32_bf16(c0.s, bl[0], acc[0][0], 0, 0, 0);
    acc[0][1] = __builtin_amdgcn_mfma_f32_16x16x32_bf16(c0.s, bl[1], acc[0][1], 0, 0, 0);
    acc[1][0] = __builtin_amdgcn_mfma_f32_16x16x32_bf16(c1.s, bh[0], acc[1][0], 0, 0, 0);
    acc[1][1] = __builtin_amdgcn_mfma_f32_16x16x32_bf16(c1.s, bh[1], acc[1][1], 0, 0, 0);
    acc[1][0] = __builtin_amdgcn_mfma_f32_16x16x32_bf16(c1.s, bl[0], acc[1][0], 0, 0, 0);
    acc[1][1] = __builtin_amdgcn_mfma_f32_16x16x32_bf16(c1.s, bl[1], acc[1][1], 0, 0, 0);
    // im=2..7 inline (tab reads interleave under the MFMAs above)
    #pragma unroll
    for (int im = 2; im < 8; ++im){
      u32 by = aw[im] >> qs;
      union { u64 d[2]; short8 s; } c;
      c.d[0] = tab[by & 15u];
      c.d[1] = tab[(by >> 4) & 15u];
      acc[im][0] = __builtin_amdgcn_mfma_f32_16x16x32_bf16(c.s, bh[0], acc[im][0], 0, 0, 0);
      acc[im][1] = __builtin_amdgcn_mfma_f32_16x16x32_bf16(c.s, bh[1], acc[im][1], 0, 0, 0);
      acc[im][0] = __builtin_amdgcn_mfma_f32_16x16x32_bf16(c.s, bl[0], acc[im][0], 0, 0, 0);
      acc[im][1] = __builtin_amdgcn_mfma_f32_16x16x32_bf16(c.s, bl[1], acc[im][1], 0, 0, 0);
    }
    __builtin_amdgcn_s_setprio(0);
    // prefetch A-words for the NEXT iteration (skip if next iter starts a new chunk)
    int nkb = kb + 32;
    if (nkb < KH && (nkb & 255) != 0) loadA((nkb >> 5) & 7);
    // refill own buffer with tile k+2 (wave-local; MFMAs consumed buf cur already).
    if (kb + 64 < KH) stageB(cur, kb + 64);
    cur ^= 1;
  }

  if (mode == 0 || mode == 3){
    float* X = (float*)smemraw;   // [128][132] f32 exchange (GROUPS=2), reuses B region
    if constexpr (GROUPS == 2){
      __syncthreads();            // all waves done with B/A LDS
      if (grp == 1){
        #pragma unroll
        for (int im = 0; im < 8; ++im){
          int row0 = im * 16 + quad * 4;
          #pragma unroll
          for (int in = 0; in < 2; ++in){
            int cl_ = wn + in * 16 + lm;
            #pragma unroll
            for (int r = 0; r < 4; ++r)
              X[(row0 + r) * 132 + cl_] = acc[im][in][r];
          }
        }
      }
      __syncthreads();
      if (grp == 1) return;
    }
    #pragma unroll
    for (int im = 0; im < 8; ++im){
      int row0 = im * 16 + quad * 4;
      #pragma unroll
      for (int in = 0; in < 2; ++in){
        int col = n0 + wn + in * 16 + lm;
        float bv = bias ? bias[col] : 0.f;
        #pragma unroll
        for (int r = 0; r < 4; ++r){
          int row = row0 + r;
          int t = row >> 5; int bq = bn0 + (row & 31);
          size_t gg = (size_t)t * 4096 + bq;
          float vv = acc[im][in][r] + bv + xtio[gg * 512 + col];
          if constexpr (GROUPS == 2) vv += X[row * 132 + wn + in * 16 + lm];
          if (mode == 0){
            xtio[gg * 512 + col] = vv;
          } else {
            outF[(((size_t)t * 16 + (bq >> 8)) * 512 + col) * 256 + (bq & 255)] = vv;
          }
        }
      }
    }
    return;
  }

  if constexpr (GROUPS == 1){
    // modes 1/2: pure-register LIF (all 4 timesteps of a token live in one lane),
    // ballot -> bit-packed output. token A = quad*4+r (im=2t), token B = 16+quad*4+r
    __syncthreads();  // waves free-run in the loop; all must finish Alds reads before reuse
    u32* bits32 = (u32*)(smemraw + 32768);         // [128][4] u32, reuses Alds region
    u64* ob; int obrs, obwb;
    if (mode == 1){ ob = outBits + (size_t)(n0 >> 9) * 131072; obrs = 8; obwb = (n0 & 511) >> 6; }
    else          { ob = outBits; obrs = 32; obwb = n0 >> 6; }
    float D = sigmoidf_(lifw[mode == 1 ? (2 + (n0 >> 9)) : lidx]);
    float bv0 = bias ? bias[n0 + wn + lm] : 0.f;
    float bv1 = bias ? bias[n0 + wn + 16 + lm] : 0.f;
    #pragma unroll
    for (int r = 0; r < 4; ++r){
      float vA0 = 0.f, vA1 = 0.f, vB0 = 0.f, vB1 = 0.f;
      #pragma unroll
      for (int t = 0; t < 4; ++t){
        float pA0 = acc[2*t][0][r] + bv0;   vA0 += (pA0 - vA0) * D; bool sA0 = vA0 >= 1.f; vA0 = sA0 ? 0.f : vA0;
        float pA1 = acc[2*t][1][r] + bv1;   vA1 += (pA1 - vA1) * D; bool sA1 = vA1 >= 1.f; vA1 = sA1 ? 0.f : vA1;
        float pB0 = acc[2*t+1][0][r] + bv0; vB0 += (pB0 - vB0) * D; bool sB0 = vB0 >= 1.f; vB0 = sB0 ? 0.f : vB0;
        float pB1 = acc[2*t+1][1][r] + bv1; vB1 += (pB1 - vB1) * D; bool sB1 = vB1 >= 1.f; vB1 = sB1 ? 0.f : vB1;
        u64 balA0 = __ballot(sA0), balA1 = __ballot(sA1);
        u64 balB0 = __ballot(sB0), balB1 = __ballot(sB1);
        if (lane < 4){
          int q = lane;
          u32 wA = (u32)((balA0 >> (16*q)) & 0xFFFFull) | ((u32)((balA1 >> (16*q)) & 0xFFFFull) << 16);
          u32 wB = (u32)((balB0 >> (16*q)) & 0xFFFFull) | ((u32)((balB1 >> (16*q)) & 0xFFFFull) << 16);
          bits32[(t * 32 + q * 4 + r) * 4 + wid]      = wA;
          bits32[(t * 32 + 16 + q * 4 + r) * 4 + wid] = wB;
        }
      }
    }
    __syncthreads();
    {
      int t = tid >> 6, bnl = (tid >> 1) & 31, j = tid & 1;
      size_t g = (size_t)t * 4096 + bn0 + bnl;
      int idx = (t * 32 + bnl) * 4 + 2 * j;
      u64 wv64 = (u64)bits32[idx] | ((u64)bits32[idx + 1] << 32);
      ob[g * obrs + obwb + j] = wv64;
    }
  }
}

// ---- attention pre-acts per (t,b,h): a = (q @ kvm) * 0.125 via MFMA, kvm by popcount ----
__global__ __launch_bounds__(256) void attn_a_kernel(const u64* __restrict__ bits,
    float* __restrict__ aout){
  int tbh = blockIdx.x;
  int h = tbh & 7, b = (tbh >> 3) & 15, t = tbh >> 7;
  int m0 = t * 4096 + b * 256;
  int tid = threadIdx.x, lane = tid & 63, wid = tid >> 6;
  __shared__ u64 QW[256], KW[256], VW[256];
  __shared__ u64 kbt[64][4], vbt[64][4];
  __shared__ __align__(16) unsigned short Bs[64 * 72];
  {
    size_t base = (size_t)(m0 + tid) * 8 + h;
    QW[tid] = bits[base];
    KW[tid] = bits[131072 + base];
    VW[tid] = bits[262144 + base];
  }
  __syncthreads();
  {
    int i = tid & 63, w = tid >> 6;
    const u64* kwp = &KW[w * 64];
    const u64* vwp = &VW[w * 64];
    u64 bk = 0, bv = 0;
    for (int nn = 0; nn < 64; ++nn){
      bk |= ((kwp[nn] >> i) & 1ull) << nn;
      bv |= ((vwp[nn] >> i) & 1ull) << nn;
    }
    kbt[i][w] = bk; vbt[i][w] = bv;
  }
  __syncthreads();
  #pragma unroll
  for (int e = 0; e < 16; ++e){
    int idx = tid * 16 + e;
    int i = idx >> 6, j = idx & 63;
    int cnt = __popcll(kbt[i][0] & vbt[j][0]) + __popcll(kbt[i][1] & vbt[j][1])
            + __popcll(kbt[i][2] & vbt[j][2]) + __popcll(kbt[i][3] & vbt[j][3]);
    Bs[j * 72 + i] = f2b((float)cnt);
  }
  __syncthreads();
  int lm = lane & 15, quad = lane >> 4;
  int wm = wid * 64;
  u64 qw[4];
  #pragma unroll
  for (int im = 0; im < 4; ++im) qw[im] = QW[wm + im * 16 + lm];
  floatx4 acc[4][4];
  #pragma unroll
  for (int i = 0; i < 4; ++i)
    #pragma unroll
    for (int j = 0; j < 4; ++j){ acc[i][j][0]=0.f; acc[i][j][1]=0.f; acc[i][j][2]=0.f; acc[i][j][3]=0.f; }
  #pragma unroll
  for (int kb = 0; kb < 64; kb += 32){
    short8 af[4], bf[4];
    #pragma unroll
    for (int im = 0; im < 4; ++im){
      u32 byte = (u32)(qw[im] >> (kb + quad * 8)) & 0xFFu;
      union { u32 u[4]; short8 s; } c;
      c.u[0] = ((byte & 1u)        | ((byte & 2u) << 15))        * 0x3F80u;
      c.u[1] = (((byte >> 2) & 1u) | (((byte >> 3) & 1u) << 16)) * 0x3F80u;
      c.u[2] = (((byte >> 4) & 1u) | (((byte >> 5) & 1u) << 16)) * 0x3F80u;
      c.u[3] = (((byte >> 6) & 1u) | (((byte >> 7) & 1u) << 16)) * 0x3F80u;
      af[im] = c.s;
    }
    #pragma unroll
    for (int in = 0; in < 4; ++in)
      bf[in] = *(const short8*)(&Bs[(in * 16 + lm) * 72 + kb + quad * 8]);
    #pragma unroll
    for (int im = 0; im < 4; ++im)
      #pragma unroll
      for (int in = 0; in < 4; ++in)
        acc[im][in] = __builtin_amdgcn_mfma_f32_16x16x32_bf16(af[im], bf[in], acc[im][in], 0, 0, 0);
  }
  float* ob = aout + (size_t)m0 * 512 + h * 64;
  #pragma unroll
  for (int im = 0; im < 4; ++im){
    int nr0 = wm + im * 16 + quad * 4;
    #pragma unroll
    for (int in = 0; in < 4; ++in){
      int j = in * 16 + lm;
      #pragma unroll
      for (int r = 0; r < 4; ++r)
        ob[(size_t)(nr0 + r) * 512 + j] = acc[im][in][r] * 0.125f;
    }
  }
}

extern "C" void kernel_launch(void* const* d_in, const int* in_sizes, int n_in,
                              void* d_out, int out_size, void* d_ws, size_t ws_size,
                              hipStream_t stream){
  const float* x     = (const float*)d_in[0];
  const float* convw = (const float*)d_in[1];
  const float* convb = (const float*)d_in[2];
  const float* ln1g  = (const float*)d_in[3];
  const float* ln1b  = (const float*)d_in[4];
  const float* qkvw  = (const float*)d_in[5];
  const float* projw = (const float*)d_in[6];
  const float* projb = (const float*)d_in[7];
  const float* ln2g  = (const float*)d_in[8];
  const float* ln2b  = (const float*)d_in[9];
  const float* fc1w  = (const float*)d_in[10];
  const float* fc1b  = (const float*)d_in[11];
  const float* fc2w  = (const float*)d_in[12];
  const float* fc2b  = (const float*)d_in[13];
  const float* lifw  = (const float*)d_in[14];
  float* outp = (float*)d_out;

  // workspace layout (~89 MB)
  char* wsb = (char*)d_ws;
  float* XT           = (float*)wsb;                           // [16384,512] f32  33.5 MB
  float* AF32         = (float*)(wsb + 33554432);              // [16384,512] f32  33.5 MB
  unsigned short* WHI = (unsigned short*)(wsb + 67108864);     //  6.3 MB
  unsigned short* WLO = (unsigned short*)(wsb + 73400320);     //  6.3 MB
  u64* QBITS          = (u64*)(wsb + 79691776);                // [3,16384,8]  3.1 MB
  u64* H12            = (u64*)(wsb + 82837504);                // [16384,8]    1.0 MB
  u64* ASB            = (u64*)(wsb + 83886080);                // [16384,8]    1.0 MB
  u64* HBITS          = (u64*)(wsb + 84934656);                // [16384,32]   4.2 MB
  const int OFF_QKV = 0, OFF_PROJ = 786432, OFF_FC1 = 1048576, OFF_FC2 = 2097152;
  const int LDS1 = 36992;  // 32K (B dbuf) + 4K (A chunk) + 128 (LUT) -> 4 blocks/CU
  const int LDS2 = 73856;  // 64K (2 groups B) + 8K (A chunks) + 128 -> 2 blocks/CU

  wsplit_kernel<<<12288, 256, 0, stream>>>(qkvw, projw, fc1w, fc2w, WHI, WLO);
  conv_lif_kernel<<<512, 256, 0, stream>>>(x, convw, convb, lifw, XT);
  // h1 bits
  ln_lif_kernel<<<4096, 256, 0, stream>>>(XT, ln1g, ln1b, lifw, 1, H12);
  // qkv GEMM + LIF -> bit-packed q,k,v
  gemm_fused<1><<<dim3(128, 12), 256, LDS1, stream>>>(H12, 8,
      WHI + OFF_QKV, WLO + OFF_QKV, 512, nullptr,
      nullptr, nullptr, QBITS, 512, 1, lifw, 0);
  // attention pre-acts
  attn_a_kernel<<<512, 256, 0, stream>>>(QBITS, AF32);
  // a_s bits
  lif_bits_kernel<<<8192, 256, 0, stream>>>(AF32, ASB, lifw, 5);
  // xt += a_s @ proj^T + proj_b   (in-block K-split, 512 threads)
  gemm_fused<2><<<dim3(128, 4), 512, LDS2, stream>>>(ASB, 8,
      WHI + OFF_PROJ, WLO + OFF_PROJ, 512, projb,
      XT, nullptr, nullptr, 512, 0, lifw, 0);
  // h2 bits
  ln_lif_kernel<<<4096, 256, 0, stream>>>(XT, ln2g, ln2b, lifw, 6, H12);
  // fc1 (merged, N=2048) + LIF -> HBITS
  gemm_fused<1><<<dim3(128, 16), 256, LDS1, stream>>>(H12, 8,
      WHI + OFF_FC1, WLO + OFF_FC1, 512, fc1b,
      nullptr, nullptr, HBITS, 512, 2, lifw, 7);
  // fc2 (merged, K=2048) + residual -> final transposed output (in-block K-split)
  gemm_fused<2><<<dim3(128, 4), 512, LDS2, stream>>>(HBITS, 32,
      WHI + OFF_FC2, WLO + OFF_FC2, 2048, fc2b,
      XT, outp, nullptr, 2048, 3, lifw, 0);
}